// Round 1
// baseline (1264.134 us; speedup 1.0000x reference)
//
#include <hip/hip_runtime.h>

#define L_SEQ 2048
#define NB    2
#define DMOD  1024
#define DIN   2048
#define NST   16
#define NROWS (NB*L_SEQ)   // 4096

__device__ __forceinline__ float siluf(float v){ return v / (1.f + __expf(-v)); }

// ---------------- GEMM: 128x128 tile, BK=8, 256 threads, 8x8 per thread ----------------
// EPI==0: C0[row*N+col] = v
// EPI==1: split at N/2: col<half -> C0[row*half+col]=v ; else C1[row*half+col-half]=silu(v)
template<int EPI>
__global__ __launch_bounds__(256)
void gemm128(const float* __restrict__ A, const float* __restrict__ B,
             float* __restrict__ C0, float* __restrict__ C1,
             int M, int N, int K)
{
    __shared__ float As[8][136];   // [k][m], padded (stride 136 keeps 16B align, 2-way bank max)
    __shared__ float Bs[8][128];   // [k][n]
    const int tid = threadIdx.x;
    const int bm = blockIdx.y * 128;
    const int bn = blockIdx.x * 128;
    const int tm = (tid >> 4) << 3;
    const int tn = (tid & 15) << 3;

    const int arow = tid >> 1;
    const int akq  = (tid & 1) << 2;
    const int brow = tid >> 5;
    const int bcol = (tid & 31) << 2;

    float acc[8][8];
    #pragma unroll
    for (int i = 0; i < 8; i++)
        #pragma unroll
        for (int j = 0; j < 8; j++) acc[i][j] = 0.f;

    for (int k0 = 0; k0 < K; k0 += 8) {
        float4 av = *(const float4*)&A[(size_t)(bm + arow) * K + k0 + akq];
        float4 bv = *(const float4*)&B[(size_t)(k0 + brow) * N + bn + bcol];
        __syncthreads();
        As[akq + 0][arow] = av.x;
        As[akq + 1][arow] = av.y;
        As[akq + 2][arow] = av.z;
        As[akq + 3][arow] = av.w;
        *(float4*)&Bs[brow][bcol] = bv;
        __syncthreads();
        #pragma unroll
        for (int k = 0; k < 8; k++) {
            float4 a0 = *(const float4*)&As[k][tm];
            float4 a1 = *(const float4*)&As[k][tm + 4];
            float4 b0 = *(const float4*)&Bs[k][tn];
            float4 b1 = *(const float4*)&Bs[k][tn + 4];
            float av8[8] = {a0.x,a0.y,a0.z,a0.w,a1.x,a1.y,a1.z,a1.w};
            float bv8[8] = {b0.x,b0.y,b0.z,b0.w,b1.x,b1.y,b1.z,b1.w};
            #pragma unroll
            for (int i = 0; i < 8; i++)
                #pragma unroll
                for (int j = 0; j < 8; j++)
                    acc[i][j] = fmaf(av8[i], bv8[j], acc[i][j]);
        }
    }

    if (EPI == 0) {
        #pragma unroll
        for (int i = 0; i < 8; i++) {
            int row = bm + tm + i;
            #pragma unroll
            for (int j = 0; j < 8; j += 4) {
                float4 v = {acc[i][j], acc[i][j+1], acc[i][j+2], acc[i][j+3]};
                *(float4*)&C0[(size_t)row * N + bn + tn + j] = v;
            }
        }
    } else {
        const int half = N >> 1;
        #pragma unroll
        for (int i = 0; i < 8; i++) {
            int row = bm + tm + i;
            #pragma unroll
            for (int j = 0; j < 8; j++) {
                int col = bn + tn + j;
                float v = acc[i][j];
                if (col < half) C0[(size_t)row * half + col] = v;
                else            C1[(size_t)row * half + col - half] = siluf(v);
            }
        }
    }
}

// ---------------- depthwise causal conv (4 taps) + bias + SiLU ----------------
__global__ __launch_bounds__(256)
void conv_silu(const float* __restrict__ xin, const float* __restrict__ cw,
               const float* __restrict__ cb, float* __restrict__ xc)
{
    int idx = blockIdx.x * 256 + threadIdx.x;      // over NB*L*DIN/4
    int d4 = idx & (DIN/4 - 1);
    int t  = (idx / (DIN/4)) & (L_SEQ - 1);
    int b  = idx / ((DIN/4) * L_SEQ);
    int d  = d4 << 2;
    const float4* cw4 = (const float4*)cw;         // channel c taps = cw4[c]
    float4 w0 = cw4[d + 0], w1 = cw4[d + 1], w2 = cw4[d + 2], w3 = cw4[d + 3];
    float4 acc = *(const float4*)&cb[d];
    #pragma unroll
    for (int k = 0; k < 4; k++) {
        int tt = t + k - 3;
        if (tt >= 0) {
            float4 v = *(const float4*)&xin[((size_t)(b * L_SEQ + tt)) * DIN + d];
            acc.x += v.x * (&w0.x)[k];
            acc.y += v.y * (&w1.x)[k];
            acc.z += v.z * (&w2.x)[k];
            acc.w += v.w * (&w3.x)[k];
        }
    }
    acc.x = siluf(acc.x); acc.y = siluf(acc.y); acc.z = siluf(acc.z); acc.w = siluf(acc.w);
    *(float4*)&xc[(size_t)idx * 4] = acc;
}

// ---------------- W_x transpose (2048x33 -> 33x2048) ----------------
__global__ void transpose_wx(const float* __restrict__ Wx, float* __restrict__ WxT)
{
    int idx = blockIdx.x * 256 + threadIdx.x;
    if (idx >= 33 * DIN) return;
    int n = idx / DIN, k = idx - n * DIN;
    WxT[idx] = Wx[k * 33 + n];
}

// ---------------- GEMM2: one wave per row, 33 outputs, softplus on col 0 ----------------
__global__ __launch_bounds__(256)
void gemm2_params(const float* __restrict__ xc, const float* __restrict__ WxT,
                  float* __restrict__ delta, float* __restrict__ Bm, float* __restrict__ Cm)
{
    int gtid = blockIdx.x * 256 + threadIdx.x;
    int row  = gtid >> 6;
    int lane = gtid & 63;
    const float* xr = xc + (size_t)row * DIN;
    float x[32];
    #pragma unroll
    for (int j = 0; j < 32; j++) x[j] = xr[lane + (j << 6)];
    #pragma unroll 1
    for (int n = 0; n < 33; n++) {
        const float* w = WxT + n * DIN;
        float s = 0.f;
        #pragma unroll
        for (int j = 0; j < 32; j++) s = fmaf(x[j], w[lane + (j << 6)], s);
        #pragma unroll
        for (int off = 32; off >= 1; off >>= 1) s += __shfl_xor(s, off, 64);
        if (lane == 0) {
            if (n == 0)      delta[row] = fmaxf(s, 0.f) + log1pf(__expf(-fabsf(s)));
            else if (n < 17) Bm[row * NST + (n - 1)]  = s;
            else             Cm[row * NST + (n - 17)] = s;
        }
    }
}

// ---------------- selective scan + (y + x*D)*silu_res fusion ----------------
#define TC 64
__global__ __launch_bounds__(256)
void scan_fused(const float* __restrict__ xc, const float* __restrict__ delta,
                const float* __restrict__ Bm, const float* __restrict__ Cm,
                const float* __restrict__ A_log, const float* __restrict__ Dp,
                const float* __restrict__ res, float* __restrict__ y)
{
    const int b   = blockIdx.y;
    const int d0  = blockIdx.x << 4;          // 16 channels per block
    const int tid = threadIdx.x;
    const int n   = tid & 15, dg = tid >> 4;
    const int d   = d0 + dg;
    const float Adn = -__expf(A_log[d * NST + n]);

    __shared__ float sdt[TC];
    __shared__ float sB[TC][NST], sC[TC][NST], sx[TC][NST], sr[TC][NST], sy[TC][NST];
    __shared__ float sDp[16];
    if (tid < 16) sDp[tid] = Dp[d0 + tid];

    float h = 0.f;
    for (int c0 = 0; c0 < L_SEQ; c0 += TC) {
        __syncthreads();
        if (tid < TC) sdt[tid] = delta[b * L_SEQ + c0 + tid];
        #pragma unroll
        for (int i = tid; i < TC * NST; i += 256) {
            int t = i >> 4, q = i & 15;
            int rowg = b * L_SEQ + c0 + t;
            sB[t][q] = Bm[rowg * NST + q];
            sC[t][q] = Cm[rowg * NST + q];
            sx[t][q] = xc[(size_t)rowg * DIN + d0 + q];
            sr[t][q] = res[(size_t)rowg * DIN + d0 + q];
        }
        __syncthreads();
        for (int t = 0; t < TC; ++t) {
            float dt = sdt[t];
            float a  = __expf(dt * Adn);
            h = fmaf(a, h, dt * sB[t][n] * sx[t][dg]);
            float p = sC[t][n] * h;
            p += __shfl_xor(p, 1, 16);
            p += __shfl_xor(p, 2, 16);
            p += __shfl_xor(p, 4, 16);
            p += __shfl_xor(p, 8, 16);
            if (n == 0) sy[t][dg] = p;
        }
        __syncthreads();
        #pragma unroll
        for (int i = tid; i < TC * NST; i += 256) {
            int t = i >> 4, q = i & 15;
            int rowg = b * L_SEQ + c0 + t;
            y[(size_t)rowg * DIN + d0 + q] = (sy[t][q] + sx[t][q] * sDp[q]) * sr[t][q];
        }
    }
}

extern "C" void kernel_launch(void* const* d_in, const int* in_sizes, int n_in,
                              void* d_out, int out_size, void* d_ws, size_t ws_size,
                              hipStream_t stream)
{
    const float* x     = (const float*)d_in[0];
    const float* W_in  = (const float*)d_in[1];
    const float* cw    = (const float*)d_in[2];
    const float* cb    = (const float*)d_in[3];
    const float* Wx    = (const float*)d_in[4];
    const float* A_log = (const float*)d_in[5];
    const float* Dp    = (const float*)d_in[6];
    const float* W_out = (const float*)d_in[7];
    float* out = (float*)d_out;
    float* ws  = (float*)d_ws;

    float* xin   = ws;                   // 8388608 floats (also reused as y later)
    float* res   = ws + 8388608;         // 8388608 (holds silu(res))
    float* xc    = ws + 16777216;        // 8388608
    float* delta = ws + 25165824;        // 4096
    float* Bm    = delta + 4096;         // 65536
    float* Cm    = Bm + 65536;           // 65536
    float* WxT   = Cm + 65536;           // 67584
    float* y     = xin;                  // alias: xin dead after conv

    dim3 blk(256);
    // GEMM1: x(4096x1024) @ W_in(1024x4096) -> xin | silu(res)
    gemm128<1><<<dim3(32, 32), blk, 0, stream>>>(x, W_in, xin, res, NROWS, 2 * DIN, DMOD);
    // depthwise conv + bias + silu
    conv_silu<<<dim3(NROWS * DIN / 4 / 256), blk, 0, stream>>>(xin, cw, cb, xc);
    // W_x transpose then GEMM2 (delta/B/C with softplus)
    transpose_wx<<<dim3((33 * DIN + 255) / 256), blk, 0, stream>>>(Wx, WxT);
    gemm2_params<<<dim3(NROWS / 4), blk, 0, stream>>>(xc, WxT, delta, Bm, Cm);
    // selective scan + elementwise fusion -> y
    scan_fused<<<dim3(DIN / 16, NB), blk, 0, stream>>>(xc, delta, Bm, Cm, A_log, Dp, res, y);
    // GEMM3: y(4096x2048) @ W_out(2048x1024) -> out
    gemm128<0><<<dim3(1024 / 128, NROWS / 128), blk, 0, stream>>>(y, W_out, out, nullptr, NROWS, DMOD, DIN);
}

// Round 2
// 333.451 us; speedup vs baseline: 3.7911x; 3.7911x over previous
//
#include <hip/hip_runtime.h>

#define L_SEQ 2048
#define NB    2
#define DMOD  1024
#define DIN   2048
#define NST   16
#define NROWS (NB*L_SEQ)   // 4096
#define CL    64
#define NC    (L_SEQ/CL)   // 32

typedef unsigned short u16;
typedef _Float16 half8 __attribute__((ext_vector_type(8)));
typedef float f32x4 __attribute__((ext_vector_type(4)));
typedef short short8 __attribute__((ext_vector_type(8)));

__device__ __forceinline__ float siluf(float v){ return v / (1.f + __expf(-v)); }
__device__ __forceinline__ u16 f2h_bits(float v){ _Float16 h = (_Float16)v; return __builtin_bit_cast(u16, h); }

// ---------------- fp32 -> fp16 convert (vec4) ----------------
__global__ __launch_bounds__(256)
void f32_to_f16(const float* __restrict__ in, u16* __restrict__ out, int n4)
{
    int i = blockIdx.x * 256 + threadIdx.x;
    if (i >= n4) return;
    float4 v = ((const float4*)in)[i];
    ushort4 o;
    o.x = f2h_bits(v.x); o.y = f2h_bits(v.y); o.z = f2h_bits(v.z); o.w = f2h_bits(v.w);
    *(ushort4*)&out[(size_t)i * 4] = o;
}

// ---------------- transpose fp32 [R][C] -> fp16 [C][R] ----------------
__global__ __launch_bounds__(256)
void transpose_to_f16(const float* __restrict__ in, u16* __restrict__ outT, int R, int C)
{
    __shared__ float s[64][65];
    int r0 = blockIdx.y * 64, c0 = blockIdx.x * 64;
    int tc = threadIdx.x & 63, ty = threadIdx.x >> 6;
    #pragma unroll
    for (int j = 0; j < 16; j++) {
        int r = ty + j * 4;
        s[r][tc] = in[(size_t)(r0 + r) * C + c0 + tc];
    }
    __syncthreads();
    #pragma unroll
    for (int j = 0; j < 16; j++) {
        int nn = ty + j * 4;                       // column of input = row of outT
        outT[(size_t)(c0 + nn) * R + r0 + tc] = f2h_bits(s[tc][nn]);
    }
}

// ---------------- MFMA GEMM: C[M][N] = A[M][K] * Bt[N][K]^T (fp16 in, fp32 out) ----------------
// 128x128 tile, BK=64, 256 threads = 4 waves (2x2), each wave 64x64 via 4x4 frags of 16x16x32.
// EPI==0: C0[row*N+col]=v ; EPI==1: split at N/2 -> C0=xin, C1=silu(res)
template<int EPI>
__global__ __launch_bounds__(256)
void gemm_mfma(const u16* __restrict__ A, const u16* __restrict__ Bt,
               float* __restrict__ C0, float* __restrict__ C1,
               int M, int N, int K)
{
    __shared__ __align__(16) u16 As[128 * 64];   // [row][64 k], 16B-unit slot = unit ^ (row&7)
    __shared__ __align__(16) u16 Bs[128 * 64];
    const int tid  = threadIdx.x;
    const int lane = tid & 63;
    const int wid  = tid >> 6;
    const int wm   = wid >> 1, wn = wid & 1;
    const int bm = blockIdx.y * 128, bn = blockIdx.x * 128;

    const int srow  = tid >> 3;          // 0..31
    const int sunit = tid & 7;           // which 8-elem (16B) unit within 64-col row
    const u16* Ag = A  + (size_t)bm * K;
    const u16* Bg = Bt + (size_t)bn * K;

    f32x4 acc[4][4];
    #pragma unroll
    for (int i = 0; i < 4; i++)
        #pragma unroll
        for (int j = 0; j < 4; j++)
            acc[i][j] = (f32x4){0.f, 0.f, 0.f, 0.f};

    short8 ra[4], rb[4];
    #pragma unroll
    for (int j = 0; j < 4; j++) {
        int row = j * 32 + srow;
        ra[j] = *(const short8*)&Ag[(size_t)row * K + sunit * 8];
        rb[j] = *(const short8*)&Bg[(size_t)row * K + sunit * 8];
    }

    for (int k0 = 0; k0 < K; k0 += 64) {
        __syncthreads();   // prior iteration's LDS reads done
        #pragma unroll
        for (int j = 0; j < 4; j++) {
            int row  = j * 32 + srow;
            int slot = sunit ^ (row & 7);
            *(short8*)&As[row * 64 + slot * 8] = ra[j];
            *(short8*)&Bs[row * 64 + slot * 8] = rb[j];
        }
        __syncthreads();
        if (k0 + 64 < K) {
            #pragma unroll
            for (int j = 0; j < 4; j++) {
                int row = j * 32 + srow;
                ra[j] = *(const short8*)&Ag[(size_t)row * K + k0 + 64 + sunit * 8];
                rb[j] = *(const short8*)&Bg[(size_t)row * K + k0 + 64 + sunit * 8];
            }
        }
        #pragma unroll
        for (int kk = 0; kk < 2; kk++) {
            half8 af[4], bf[4];
            #pragma unroll
            for (int mi = 0; mi < 4; mi++) {
                int row  = wm * 64 + mi * 16 + (lane & 15);
                int slot = (kk * 4 + (lane >> 4)) ^ (row & 7);
                af[mi] = *(const half8*)&As[row * 64 + slot * 8];
            }
            #pragma unroll
            for (int ni = 0; ni < 4; ni++) {
                int row  = wn * 64 + ni * 16 + (lane & 15);
                int slot = (kk * 4 + (lane >> 4)) ^ (row & 7);
                bf[ni] = *(const half8*)&Bs[row * 64 + slot * 8];
            }
            #pragma unroll
            for (int mi = 0; mi < 4; mi++)
                #pragma unroll
                for (int ni = 0; ni < 4; ni++)
                    acc[mi][ni] = __builtin_amdgcn_mfma_f32_16x16x32_f16(af[mi], bf[ni], acc[mi][ni], 0, 0, 0);
        }
    }

    const int cr = (lane >> 4) * 4;
    const int cc = lane & 15;
    #pragma unroll
    for (int mi = 0; mi < 4; mi++) {
        #pragma unroll
        for (int ni = 0; ni < 4; ni++) {
            #pragma unroll
            for (int q = 0; q < 4; q++) {
                int row = bm + wm * 64 + mi * 16 + cr + q;
                int col = bn + wn * 64 + ni * 16 + cc;
                float v = acc[mi][ni][q];
                if (EPI == 0) {
                    C0[(size_t)row * N + col] = v;
                } else {
                    int half = N >> 1;
                    if (col < half) C0[(size_t)row * half + col] = v;
                    else            C1[(size_t)row * half + col - half] = siluf(v);
                }
            }
        }
    }
}

// ---------------- depthwise causal conv (4 taps) + bias + SiLU ----------------
__global__ __launch_bounds__(256)
void conv_silu(const float* __restrict__ xin, const float* __restrict__ cw,
               const float* __restrict__ cb, float* __restrict__ xc)
{
    int idx = blockIdx.x * 256 + threadIdx.x;      // over NB*L*DIN/4
    int d4 = idx & (DIN/4 - 1);
    int t  = (idx / (DIN/4)) & (L_SEQ - 1);
    int b  = idx / ((DIN/4) * L_SEQ);
    int d  = d4 << 2;
    const float4* cw4 = (const float4*)cw;
    float4 w0 = cw4[d + 0], w1 = cw4[d + 1], w2 = cw4[d + 2], w3 = cw4[d + 3];
    float4 acc = *(const float4*)&cb[d];
    #pragma unroll
    for (int k = 0; k < 4; k++) {
        int tt = t + k - 3;
        if (tt >= 0) {
            float4 v = *(const float4*)&xin[((size_t)(b * L_SEQ + tt)) * DIN + d];
            acc.x += v.x * (&w0.x)[k];
            acc.y += v.y * (&w1.x)[k];
            acc.z += v.z * (&w2.x)[k];
            acc.w += v.w * (&w3.x)[k];
        }
    }
    acc.x = siluf(acc.x); acc.y = siluf(acc.y); acc.z = siluf(acc.z); acc.w = siluf(acc.w);
    *(float4*)&xc[(size_t)idx * 4] = acc;
}

// ---------------- W_x transpose (2048x33 -> 33x2048, fp32) ----------------
__global__ void transpose_wx(const float* __restrict__ Wx, float* __restrict__ WxT)
{
    int idx = blockIdx.x * 256 + threadIdx.x;
    if (idx >= 33 * DIN) return;
    int n = idx / DIN, k = idx - n * DIN;
    WxT[idx] = Wx[k * 33 + n];
}

// ---------------- GEMM2: one wave per row, 33 outputs, softplus on col 0 ----------------
__global__ __launch_bounds__(256)
void gemm2_params(const float* __restrict__ xc, const float* __restrict__ WxT,
                  float* __restrict__ delta, float* __restrict__ Bm, float* __restrict__ Cm)
{
    int gtid = blockIdx.x * 256 + threadIdx.x;
    int row  = gtid >> 6;
    int lane = gtid & 63;
    const float* xr = xc + (size_t)row * DIN;
    float x[32];
    #pragma unroll
    for (int j = 0; j < 32; j++) x[j] = xr[lane + (j << 6)];
    #pragma unroll 1
    for (int n = 0; n < 33; n++) {
        const float* w = WxT + n * DIN;
        float s = 0.f;
        #pragma unroll
        for (int j = 0; j < 32; j++) s = fmaf(x[j], w[lane + (j << 6)], s);
        #pragma unroll
        for (int off = 32; off >= 1; off >>= 1) s += __shfl_xor(s, off, 64);
        if (lane == 0) {
            if (n == 0)      delta[row] = fmaxf(s, 0.f) + log1pf(__expf(-fabsf(s)));
            else if (n < 17) Bm[row * NST + (n - 1)]  = s;
            else             Cm[row * NST + (n - 17)] = s;
        }
    }
}

// ---------------- scan pass 1: per-chunk local state + decay product ----------------
__global__ __launch_bounds__(256)
void scan_part1(const float* __restrict__ xc, const float* __restrict__ delta,
                const float* __restrict__ Bm, const float* __restrict__ A_log,
                float* __restrict__ h_loc, float* __restrict__ Pc)
{
    const int b = blockIdx.z, c = blockIdx.y, d0 = blockIdx.x << 4;
    const int tid = threadIdx.x, n = tid & 15, dg = tid >> 4, d = d0 + dg;
    const float Adn = -__expf(A_log[d * NST + n]);
    __shared__ float sdt[CL];
    __shared__ float sB[CL][NST], sx[CL][NST];
    const int t0 = c * CL;
    if (tid < CL) sdt[tid] = delta[b * L_SEQ + t0 + tid];
    for (int i = tid; i < CL * NST; i += 256) {
        int t = i >> 4, q = i & 15;
        int rowg = b * L_SEQ + t0 + t;
        sB[t][q] = Bm[rowg * NST + q];
        sx[t][q] = xc[(size_t)rowg * DIN + d0 + q];
    }
    __syncthreads();
    float h = 0.f, P = 1.f;
    for (int t = 0; t < CL; ++t) {
        float dt = sdt[t];
        float a = __expf(dt * Adn);
        P *= a;
        h = fmaf(a, h, dt * sB[t][n] * sx[t][dg]);
    }
    size_t idx = ((size_t)((b * NC + c) * DIN + d) << 4) + n;
    h_loc[idx] = h;
    Pc[idx] = P;
}

// ---------------- scan pass 2: sequential carry across 32 chunks ----------------
__global__ __launch_bounds__(256)
void scan_carry(const float* __restrict__ h_loc, const float* __restrict__ Pc,
                float* __restrict__ H_in)
{
    int gid = blockIdx.x * 256 + threadIdx.x;      // NB*DIN*NST = 65536
    int b = gid >> 15, r = gid & 32767;
    float H = 0.f;
    for (int c = 0; c < NC; ++c) {
        size_t idx = ((size_t)(b * NC + c) << 15) + r;
        H_in[idx] = H;
        H = fmaf(Pc[idx], H, h_loc[idx]);
    }
}

// ---------------- scan pass 3: per-chunk full scan from H_in + fused epilogue -> y fp16 ----------------
__global__ __launch_bounds__(256)
void scan_part3(const float* __restrict__ xc, const float* __restrict__ delta,
                const float* __restrict__ Bm, const float* __restrict__ Cm,
                const float* __restrict__ A_log, const float* __restrict__ Dp,
                const float* __restrict__ res, const float* __restrict__ H_in,
                u16* __restrict__ yh)
{
    const int b = blockIdx.z, c = blockIdx.y, d0 = blockIdx.x << 4;
    const int tid = threadIdx.x, n = tid & 15, dg = tid >> 4, d = d0 + dg;
    const float Adn = -__expf(A_log[d * NST + n]);
    __shared__ float sdt[CL], sDp[16];
    __shared__ float sB[CL][NST], sC[CL][NST], sx[CL][NST], sr[CL][NST], sy[CL][NST];
    const int t0 = c * CL;
    if (tid < CL) sdt[tid] = delta[b * L_SEQ + t0 + tid];
    if (tid < 16) sDp[tid] = Dp[d0 + tid];
    for (int i = tid; i < CL * NST; i += 256) {
        int t = i >> 4, q = i & 15;
        int rowg = b * L_SEQ + t0 + t;
        sB[t][q] = Bm[rowg * NST + q];
        sC[t][q] = Cm[rowg * NST + q];
        sx[t][q] = xc[(size_t)rowg * DIN + d0 + q];
        sr[t][q] = res[(size_t)rowg * DIN + d0 + q];
    }
    __syncthreads();
    float h = H_in[((size_t)((b * NC + c) * DIN + d) << 4) + n];
    for (int t = 0; t < CL; ++t) {
        float dt = sdt[t];
        float a = __expf(dt * Adn);
        h = fmaf(a, h, dt * sB[t][n] * sx[t][dg]);
        float p = sC[t][n] * h;
        p += __shfl_xor(p, 1, 16);
        p += __shfl_xor(p, 2, 16);
        p += __shfl_xor(p, 4, 16);
        p += __shfl_xor(p, 8, 16);
        if (n == 0) sy[t][dg] = p;
    }
    __syncthreads();
    for (int i = tid; i < CL * NST; i += 256) {
        int t = i >> 4, q = i & 15;
        int rowg = b * L_SEQ + t0 + t;
        float v = (sy[t][q] + sx[t][q] * sDp[q]) * sr[t][q];
        yh[(size_t)rowg * DIN + d0 + q] = f2h_bits(v);
    }
}

extern "C" void kernel_launch(void* const* d_in, const int* in_sizes, int n_in,
                              void* d_out, int out_size, void* d_ws, size_t ws_size,
                              hipStream_t stream)
{
    const float* x     = (const float*)d_in[0];
    const float* W_in  = (const float*)d_in[1];
    const float* cw    = (const float*)d_in[2];
    const float* cb    = (const float*)d_in[3];
    const float* Wx    = (const float*)d_in[4];
    const float* A_log = (const float*)d_in[5];
    const float* Dp    = (const float*)d_in[6];
    const float* W_out = (const float*)d_in[7];
    float* out = (float*)d_out;
    float* ws  = (float*)d_ws;

    // workspace layout (float slots); lifetimes allow the aliases noted
    float* xin   = ws;                    // 8388608 f32 ; later first 4194304 slots = y_f16
    float* res   = ws + 8388608;          // 8388608
    float* xc    = ws + 16777216;         // 8388608 ; pre-conv first 2097152 slots = x_f16
    float* delta = ws + 25165824;         // 4096
    float* Bm    = delta + 4096;          // 65536
    float* Cm    = Bm + 65536;            // 65536
    float* WxT   = Cm + 65536;            // 67584
    float* h_loc = ws + 25368576;         // 2097152 ; also Bt1 (8MB u16) / Bt3 (4MB u16)
    float* Pc    = ws + 27465728;         // 2097152
    float* H_in  = ws + 29562880;         // 2097152  (total 31660032 floats = 126.6 MB)

    u16* x_f16 = (u16*)xc;
    u16* Bt1   = (u16*)h_loc;             // W_in^T  [4096][1024] f16
    u16* Bt3   = (u16*)h_loc;             // W_out^T [1024][2048] f16
    u16* y_f16 = (u16*)xin;               // [4096][2048] f16

    dim3 blk(256);

    // 1) x -> fp16
    f32_to_f16<<<dim3(NROWS * DMOD / 4 / 256), blk, 0, stream>>>(x, x_f16, NROWS * DMOD / 4);
    // 2) W_in (1024x4096) -> Bt1 (4096x1024) fp16
    transpose_to_f16<<<dim3(4096 / 64, 1024 / 64), blk, 0, stream>>>(W_in, Bt1, DMOD, 2 * DIN);
    // 3) GEMM1: xin | silu(res)
    gemm_mfma<1><<<dim3(32, 32), blk, 0, stream>>>(x_f16, Bt1, xin, res, NROWS, 2 * DIN, DMOD);
    // 4) depthwise conv + bias + silu (overwrites x_f16 region)
    conv_silu<<<dim3(NROWS * DIN / 4 / 256), blk, 0, stream>>>(xin, cw, cb, xc);
    // 5) ssm params
    transpose_wx<<<dim3((33 * DIN + 255) / 256), blk, 0, stream>>>(Wx, WxT);
    gemm2_params<<<dim3(NROWS / 4), blk, 0, stream>>>(xc, WxT, delta, Bm, Cm);
    // 6) chunk-parallel scan
    scan_part1<<<dim3(DIN / 16, NC, NB), blk, 0, stream>>>(xc, delta, Bm, A_log, h_loc, Pc);
    scan_carry<<<dim3(NB * DIN * NST / 256), blk, 0, stream>>>(h_loc, Pc, H_in);
    scan_part3<<<dim3(DIN / 16, NC, NB), blk, 0, stream>>>(xc, delta, Bm, Cm, A_log, Dp, res, H_in, y_f16);
    // 7) W_out (2048x1024) -> Bt3 (1024x2048) fp16 (h_loc dead now)
    transpose_to_f16<<<dim3(1024 / 64, 2048 / 64), blk, 0, stream>>>(W_out, Bt3, DIN, DMOD);
    // 8) GEMM3: out = y @ W_out
    gemm_mfma<0><<<dim3(1024 / 128, NROWS / 128), blk, 0, stream>>>(y_f16, Bt3, out, nullptr, NROWS, DMOD, DIN);
}

// Round 3
// 208.966 us; speedup vs baseline: 6.0495x; 1.5957x over previous
//
#include <hip/hip_runtime.h>

#define L_SEQ 2048
#define NB    2
#define DMOD  1024
#define DIN   2048
#define NST   16
#define NROWS (NB*L_SEQ)   // 4096
#define CL    32
#define NC    (L_SEQ/CL)   // 64

typedef unsigned short u16;
typedef _Float16 half8 __attribute__((ext_vector_type(8)));
typedef float f32x4 __attribute__((ext_vector_type(4)));
typedef short short8 __attribute__((ext_vector_type(8)));

__device__ __forceinline__ float siluf(float v){ return v / (1.f + __expf(-v)); }
__device__ __forceinline__ u16 f2h_bits(float v){ _Float16 h = (_Float16)v; return __builtin_bit_cast(u16, h); }
__device__ __forceinline__ float h2f(u16 v){ return (float)__builtin_bit_cast(_Float16, v); }
__device__ __forceinline__ float fexp2(float x){
#if __has_builtin(__builtin_amdgcn_exp2f)
    return __builtin_amdgcn_exp2f(x);
#else
    return __expf(x * 0.69314718056f);
#endif
}

// ---------------- fp32 -> fp16 convert (vec4) ----------------
__global__ __launch_bounds__(256)
void f32_to_f16(const float* __restrict__ in, u16* __restrict__ out, int n4)
{
    int i = blockIdx.x * 256 + threadIdx.x;
    if (i >= n4) return;
    float4 v = ((const float4*)in)[i];
    ushort4 o;
    o.x = f2h_bits(v.x); o.y = f2h_bits(v.y); o.z = f2h_bits(v.z); o.w = f2h_bits(v.w);
    *(ushort4*)&out[(size_t)i * 4] = o;
}

// ---------------- transpose fp32 [R][C] -> fp16 [C][R] ----------------
__global__ __launch_bounds__(256)
void transpose_to_f16(const float* __restrict__ in, u16* __restrict__ outT, int R, int C)
{
    __shared__ float s[64][65];
    int r0 = blockIdx.y * 64, c0 = blockIdx.x * 64;
    int tc = threadIdx.x & 63, ty = threadIdx.x >> 6;
    #pragma unroll
    for (int j = 0; j < 16; j++) {
        int r = ty + j * 4;
        s[r][tc] = in[(size_t)(r0 + r) * C + c0 + tc];
    }
    __syncthreads();
    #pragma unroll
    for (int j = 0; j < 16; j++) {
        int nn = ty + j * 4;
        outT[(size_t)(c0 + nn) * R + r0 + tc] = f2h_bits(s[tc][nn]);
    }
}

// ---------------- MFMA GEMM 128x128, BK=64, 4 waves ----------------
// EPI==0: C0 = fp32 [M][N]
// EPI==1: split at N/2: col<half -> C0h[row][col] (u16) ; else C1h = silu (u16)
template<int EPI>
__global__ __launch_bounds__(256)
void gemm_mfma(const u16* __restrict__ A, const u16* __restrict__ Bt,
               void* __restrict__ C0v, void* __restrict__ C1v,
               int M, int N, int K)
{
    __shared__ __align__(16) u16 As[128 * 64];
    __shared__ __align__(16) u16 Bs[128 * 64];
    const int tid  = threadIdx.x;
    const int lane = tid & 63;
    const int wid  = tid >> 6;
    const int wm   = wid >> 1, wn = wid & 1;
    const int bm = blockIdx.y * 128, bn = blockIdx.x * 128;

    const int srow  = tid >> 3;
    const int sunit = tid & 7;
    const u16* Ag = A  + (size_t)bm * K;
    const u16* Bg = Bt + (size_t)bn * K;

    f32x4 acc[4][4];
    #pragma unroll
    for (int i = 0; i < 4; i++)
        #pragma unroll
        for (int j = 0; j < 4; j++)
            acc[i][j] = (f32x4){0.f, 0.f, 0.f, 0.f};

    short8 ra[4], rb[4];
    #pragma unroll
    for (int j = 0; j < 4; j++) {
        int row = j * 32 + srow;
        ra[j] = *(const short8*)&Ag[(size_t)row * K + sunit * 8];
        rb[j] = *(const short8*)&Bg[(size_t)row * K + sunit * 8];
    }

    for (int k0 = 0; k0 < K; k0 += 64) {
        __syncthreads();
        #pragma unroll
        for (int j = 0; j < 4; j++) {
            int row  = j * 32 + srow;
            int slot = sunit ^ (row & 7);
            *(short8*)&As[row * 64 + slot * 8] = ra[j];
            *(short8*)&Bs[row * 64 + slot * 8] = rb[j];
        }
        __syncthreads();
        if (k0 + 64 < K) {
            #pragma unroll
            for (int j = 0; j < 4; j++) {
                int row = j * 32 + srow;
                ra[j] = *(const short8*)&Ag[(size_t)row * K + k0 + 64 + sunit * 8];
                rb[j] = *(const short8*)&Bg[(size_t)row * K + k0 + 64 + sunit * 8];
            }
        }
        #pragma unroll
        for (int kk = 0; kk < 2; kk++) {
            half8 af[4], bf[4];
            #pragma unroll
            for (int mi = 0; mi < 4; mi++) {
                int row  = wm * 64 + mi * 16 + (lane & 15);
                int slot = (kk * 4 + (lane >> 4)) ^ (row & 7);
                af[mi] = *(const half8*)&As[row * 64 + slot * 8];
            }
            #pragma unroll
            for (int ni = 0; ni < 4; ni++) {
                int row  = wn * 64 + ni * 16 + (lane & 15);
                int slot = (kk * 4 + (lane >> 4)) ^ (row & 7);
                bf[ni] = *(const half8*)&Bs[row * 64 + slot * 8];
            }
            #pragma unroll
            for (int mi = 0; mi < 4; mi++)
                #pragma unroll
                for (int ni = 0; ni < 4; ni++)
                    acc[mi][ni] = __builtin_amdgcn_mfma_f32_16x16x32_f16(af[mi], bf[ni], acc[mi][ni], 0, 0, 0);
        }
    }

    const int cr = (lane >> 4) * 4;
    const int cc = lane & 15;
    #pragma unroll
    for (int mi = 0; mi < 4; mi++) {
        #pragma unroll
        for (int ni = 0; ni < 4; ni++) {
            #pragma unroll
            for (int q = 0; q < 4; q++) {
                int row = bm + wm * 64 + mi * 16 + cr + q;
                int col = bn + wn * 64 + ni * 16 + cc;
                float v = acc[mi][ni][q];
                if (EPI == 0) {
                    ((float*)C0v)[(size_t)row * N + col] = v;
                } else {
                    int half = N >> 1;
                    if (col < half) ((u16*)C0v)[(size_t)row * half + col] = f2h_bits(v);
                    else            ((u16*)C1v)[(size_t)row * half + col - half] = f2h_bits(siluf(v));
                }
            }
        }
    }
}

// ---------------- depthwise causal conv (4 taps) + bias + SiLU, fp16 io ----------------
__global__ __launch_bounds__(256)
void conv_silu16(const u16* __restrict__ xin16, const float* __restrict__ cw,
                 const float* __restrict__ cb, u16* __restrict__ xc16)
{
    int idx = blockIdx.x * 256 + threadIdx.x;      // (b,t,d8): NB*L*DIN/8
    int d8 = idx & 255;
    int t  = (idx >> 8) & (L_SEQ - 1);
    int b  = idx >> 19;
    int d  = d8 << 3;
    const float4* cw4 = (const float4*)cw;
    float4 w[8];
    #pragma unroll
    for (int j = 0; j < 8; j++) w[j] = cw4[d + j];
    float acc[8];
    {
        float4 b0 = *(const float4*)&cb[d];
        float4 b1 = *(const float4*)&cb[d + 4];
        acc[0]=b0.x; acc[1]=b0.y; acc[2]=b0.z; acc[3]=b0.w;
        acc[4]=b1.x; acc[5]=b1.y; acc[6]=b1.z; acc[7]=b1.w;
    }
    #pragma unroll
    for (int k = 0; k < 4; k++) {
        int tt = t + k - 3;
        if (tt >= 0) {
            short8 v = *(const short8*)&xin16[((size_t)(b * L_SEQ + tt)) * DIN + d];
            #pragma unroll
            for (int j = 0; j < 8; j++)
                acc[j] = fmaf(h2f((u16)v[j]), (&w[j].x)[k], acc[j]);
        }
    }
    short8 o;
    #pragma unroll
    for (int j = 0; j < 8; j++) o[j] = (short)f2h_bits(siluf(acc[j]));
    *(short8*)&xc16[(size_t)idx * 8] = o;
}

// ---------------- W_x (2048x33 fp32) -> WxT16 [48][2048] fp16, zero-padded ----------------
__global__ __launch_bounds__(256)
void transpose_wx16(const float* __restrict__ Wx, u16* __restrict__ WxT16)
{
    int idx = blockIdx.x * 256 + threadIdx.x;      // 48*2048
    int n = idx >> 11, k = idx & 2047;
    float v = (n < 33) ? Wx[k * 33 + n] : 0.f;
    WxT16[idx] = f2h_bits(v);
}

// ---------------- GEMM2: [4096][2048] @ [48][2048]^T, K-split 8, tile M=64 ----------------
__global__ __launch_bounds__(256)
void gemm2_mfma(const u16* __restrict__ A, const u16* __restrict__ Bt, float* __restrict__ pb)
{
    __shared__ __align__(16) u16 As[64 * 64];
    __shared__ __align__(16) u16 Bs[48 * 64];
    const int tid = threadIdx.x, lane = tid & 63, w = tid >> 6;
    const int bm = blockIdx.x * 64;
    const int kz = blockIdx.y;
    const int arow = tid >> 2;          // 0..63
    const int au   = (tid & 3) << 1;    // unit pair
    f32x4 acc[3];
    acc[0] = acc[1] = acc[2] = (f32x4){0.f, 0.f, 0.f, 0.f};

    for (int it = 0; it < 4; ++it) {
        const int k0 = kz * 256 + it * 64;
        short8 ra0 = *(const short8*)&A[(size_t)(bm + arow) * DIN + k0 + au * 8];
        short8 ra1 = *(const short8*)&A[(size_t)(bm + arow) * DIN + k0 + (au + 1) * 8];
        short8 rb0, rb1;
        if (tid < 192) {
            rb0 = *(const short8*)&Bt[(size_t)arow * DIN + k0 + au * 8];
            rb1 = *(const short8*)&Bt[(size_t)arow * DIN + k0 + (au + 1) * 8];
        }
        __syncthreads();
        {
            int s0 = au ^ (arow & 7), s1 = (au + 1) ^ (arow & 7);
            *(short8*)&As[arow * 64 + s0 * 8] = ra0;
            *(short8*)&As[arow * 64 + s1 * 8] = ra1;
            if (tid < 192) {
                *(short8*)&Bs[arow * 64 + s0 * 8] = rb0;
                *(short8*)&Bs[arow * 64 + s1 * 8] = rb1;
            }
        }
        __syncthreads();
        #pragma unroll
        for (int kk = 0; kk < 2; kk++) {
            int r = w * 16 + (lane & 15);
            int sl = (kk * 4 + (lane >> 4)) ^ (r & 7);
            half8 af = *(const half8*)&As[r * 64 + sl * 8];
            #pragma unroll
            for (int ni = 0; ni < 3; ni++) {
                int br = ni * 16 + (lane & 15);
                int bsl = (kk * 4 + (lane >> 4)) ^ (br & 7);
                half8 bf = *(const half8*)&Bs[br * 64 + bsl * 8];
                acc[ni] = __builtin_amdgcn_mfma_f32_16x16x32_f16(af, bf, acc[ni], 0, 0, 0);
            }
        }
    }
    #pragma unroll
    for (int ni = 0; ni < 3; ni++) {
        #pragma unroll
        for (int q = 0; q < 4; q++) {
            int row = bm + w * 16 + (lane >> 4) * 4 + q;
            int col = ni * 16 + (lane & 15);
            pb[((size_t)kz * NROWS + row) * 48 + col] = acc[ni][q];
        }
    }
}

// ---------------- GEMM2 reduce: sum 8 partials, softplus col0, split B/C ----------------
__global__ __launch_bounds__(256)
void gemm2_reduce(const float* __restrict__ pb, float* __restrict__ delta,
                  float* __restrict__ Bm, float* __restrict__ Cm)
{
    int idx = blockIdx.x * 256 + threadIdx.x;      // 4096*48
    int row = idx / 48, col = idx - row * 48;
    float s = 0.f;
    #pragma unroll
    for (int kz = 0; kz < 8; kz++) s += pb[(size_t)kz * NROWS * 48 + idx];
    if (col == 0)       delta[row] = fmaxf(s, 0.f) + log1pf(__expf(-fabsf(s)));
    else if (col < 17)  Bm[row * NST + col - 1]  = s;
    else if (col < 33)  Cm[row * NST + col - 17] = s;
}

// ---------------- scan pass 1: thread-per-d, h[16] in regs ----------------
__global__ __launch_bounds__(256)
void scan_part1_reg(const u16* __restrict__ xc16, const float* __restrict__ delta,
                    const float* __restrict__ Bm, const float* __restrict__ A_log,
                    float* __restrict__ h_loc, float* __restrict__ Pc)
{
    const int b = blockIdx.z, c = blockIdx.y;
    const int d = blockIdx.x * 256 + threadIdx.x;
    float ka[16];
    {
        const float4* Av = (const float4*)(A_log + (size_t)d * 16);
        #pragma unroll
        for (int q = 0; q < 4; q++) {
            float4 a = Av[q];
            ka[q*4+0] = -__expf(a.x) * 1.44269504f;
            ka[q*4+1] = -__expf(a.y) * 1.44269504f;
            ka[q*4+2] = -__expf(a.z) * 1.44269504f;
            ka[q*4+3] = -__expf(a.w) * 1.44269504f;
        }
    }
    float h[16];
    #pragma unroll
    for (int n = 0; n < 16; n++) h[n] = 0.f;
    float S = 0.f;
    const int rowbase = b * L_SEQ + c * CL;
    #pragma unroll 2
    for (int t = 0; t < CL; ++t) {
        const int rowg = rowbase + t;
        const float dt = delta[rowg];
        const float4* Bv = (const float4*)(Bm + (size_t)rowg * 16);
        float4 b0 = Bv[0], b1 = Bv[1], b2 = Bv[2], b3 = Bv[3];
        float bb[16] = {b0.x,b0.y,b0.z,b0.w, b1.x,b1.y,b1.z,b1.w,
                        b2.x,b2.y,b2.z,b2.w, b3.x,b3.y,b3.z,b3.w};
        const float xt = h2f(xc16[(size_t)rowg * DIN + d]);
        const float dtx = dt * xt;
        S += dt;
        #pragma unroll
        for (int n = 0; n < 16; n++) {
            float a = fexp2(dt * ka[n]);
            h[n] = fmaf(a, h[n], bb[n] * dtx);
        }
    }
    float* hp = h_loc + (((size_t)(b * NC + c) * DIN) + d) * 16;
    float* pp = Pc    + (((size_t)(b * NC + c) * DIN) + d) * 16;
    #pragma unroll
    for (int q = 0; q < 4; q++) {
        *(float4*)&hp[q*4] = (float4){h[q*4+0], h[q*4+1], h[q*4+2], h[q*4+3]};
        *(float4*)&pp[q*4] = (float4){fexp2(S*ka[q*4+0]), fexp2(S*ka[q*4+1]),
                                      fexp2(S*ka[q*4+2]), fexp2(S*ka[q*4+3])};
    }
}

// ---------------- scan pass 2: sequential carry across chunks ----------------
__global__ __launch_bounds__(256)
void scan_carry(const float* __restrict__ h_loc, const float* __restrict__ Pc,
                float* __restrict__ H_in)
{
    int gid = blockIdx.x * 256 + threadIdx.x;      // NB*DIN*NST = 65536
    int b = gid >> 15, r = gid & 32767;
    float H = 0.f;
    for (int c = 0; c < NC; ++c) {
        size_t idx = ((size_t)(b * NC + c) << 15) + r;
        H_in[idx] = H;
        H = fmaf(Pc[idx], H, h_loc[idx]);
    }
}

// ---------------- scan pass 3: thread-per-d, fused epilogue -> y fp16 ----------------
__global__ __launch_bounds__(256)
void scan_part3_reg(const u16* __restrict__ xc16, const float* __restrict__ delta,
                    const float* __restrict__ Bm, const float* __restrict__ Cm,
                    const float* __restrict__ A_log, const float* __restrict__ Dp,
                    const u16* __restrict__ res16, const float* __restrict__ H_in,
                    u16* __restrict__ yh)
{
    const int b = blockIdx.z, c = blockIdx.y;
    const int d = blockIdx.x * 256 + threadIdx.x;
    float ka[16];
    {
        const float4* Av = (const float4*)(A_log + (size_t)d * 16);
        #pragma unroll
        for (int q = 0; q < 4; q++) {
            float4 a = Av[q];
            ka[q*4+0] = -__expf(a.x) * 1.44269504f;
            ka[q*4+1] = -__expf(a.y) * 1.44269504f;
            ka[q*4+2] = -__expf(a.z) * 1.44269504f;
            ka[q*4+3] = -__expf(a.w) * 1.44269504f;
        }
    }
    float h[16];
    {
        const float4* Hv = (const float4*)(H_in + (((size_t)(b * NC + c) * DIN) + d) * 16);
        #pragma unroll
        for (int q = 0; q < 4; q++) {
            float4 v = Hv[q];
            h[q*4+0]=v.x; h[q*4+1]=v.y; h[q*4+2]=v.z; h[q*4+3]=v.w;
        }
    }
    const float Dpd = Dp[d];
    const int rowbase = b * L_SEQ + c * CL;
    #pragma unroll 2
    for (int t = 0; t < CL; ++t) {
        const int rowg = rowbase + t;
        const float dt = delta[rowg];
        const float4* Bv = (const float4*)(Bm + (size_t)rowg * 16);
        const float4* Cv = (const float4*)(Cm + (size_t)rowg * 16);
        float4 b0 = Bv[0], b1 = Bv[1], b2 = Bv[2], b3 = Bv[3];
        float4 c0 = Cv[0], c1 = Cv[1], c2 = Cv[2], c3 = Cv[3];
        float bb[16] = {b0.x,b0.y,b0.z,b0.w, b1.x,b1.y,b1.z,b1.w,
                        b2.x,b2.y,b2.z,b2.w, b3.x,b3.y,b3.z,b3.w};
        float cc[16] = {c0.x,c0.y,c0.z,c0.w, c1.x,c1.y,c1.z,c1.w,
                        c2.x,c2.y,c2.z,c2.w, c3.x,c3.y,c3.z,c3.w};
        const float xt = h2f(xc16[(size_t)rowg * DIN + d]);
        const float rt = h2f(res16[(size_t)rowg * DIN + d]);
        const float dtx = dt * xt;
        float y = 0.f;
        #pragma unroll
        for (int n = 0; n < 16; n++) {
            float a = fexp2(dt * ka[n]);
            h[n] = fmaf(a, h[n], bb[n] * dtx);
            y = fmaf(cc[n], h[n], y);
        }
        y = (y + xt * Dpd) * rt;
        yh[(size_t)rowg * DIN + d] = f2h_bits(y);
    }
}

extern "C" void kernel_launch(void* const* d_in, const int* in_sizes, int n_in,
                              void* d_out, int out_size, void* d_ws, size_t ws_size,
                              hipStream_t stream)
{
    const float* x     = (const float*)d_in[0];
    const float* W_in  = (const float*)d_in[1];
    const float* cw    = (const float*)d_in[2];
    const float* cb    = (const float*)d_in[3];
    const float* Wx    = (const float*)d_in[4];
    const float* A_log = (const float*)d_in[5];
    const float* Dp    = (const float*)d_in[6];
    const float* W_out = (const float*)d_in[7];
    float* out = (float*)d_out;
    float* ws  = (float*)d_ws;

    // workspace layout (float slot offsets)
    u16*   xin16 = (u16*)(ws);                     // [4096][2048] u16 ; later y16 alias
    u16*   y16   = (u16*)(ws);
    u16*   res16 = (u16*)(ws + 4194304);           // [4096][2048]
    u16*   xc16  = (u16*)(ws + 8388608);           // [4096][2048]
    u16*   x16   = (u16*)(ws + 12582912);          // [4096][1024] ; later Bt3 alias
    u16*   Bt3   = (u16*)(ws + 12582912);          // [1024][2048]
    u16*   Bt1   = (u16*)(ws + 14680064);          // [4096][1024] ; later pb alias
    float* pb    = ws + 14680064;                  // [8][4096][48]
    u16*   WxT16 = (u16*)(ws + 16252928);          // [48][2048]
    float* delta = ws + 16777216;                  // 4096
    float* Bm    = ws + 16781312;                  // 65536
    float* Cm    = ws + 16846848;                  // 65536
    float* h_loc = ws + 16912384;                  // 4194304
    float* Pc    = ws + 21106688;                  // 4194304
    float* H_in  = ws + 25300992;                  // 4194304 (end 29495296 floats = 118 MB)

    dim3 blk(256);

    // 1) x -> fp16
    f32_to_f16<<<dim3(NROWS * DMOD / 4 / 256), blk, 0, stream>>>(x, x16, NROWS * DMOD / 4);
    // 2) W_in (1024x4096) -> Bt1 (4096x1024) fp16
    transpose_to_f16<<<dim3(4096 / 64, 1024 / 64), blk, 0, stream>>>(W_in, Bt1, DMOD, 2 * DIN);
    // 3) GEMM1 -> xin16 | silu(res)16
    gemm_mfma<1><<<dim3(32, 32), blk, 0, stream>>>(x16, Bt1, xin16, res16, NROWS, 2 * DIN, DMOD);
    // 4) conv + bias + silu (fp16 io)
    conv_silu16<<<dim3(NB * L_SEQ * (DIN / 8) / 256), blk, 0, stream>>>(xin16, cw, cb, xc16);
    // 5) ssm params: W_x^T fp16 (pad 48), MFMA K-split GEMM, reduce+softplus
    transpose_wx16<<<dim3(48 * DIN / 256), blk, 0, stream>>>(Wx, WxT16);
    gemm2_mfma<<<dim3(NROWS / 64, 8), blk, 0, stream>>>(xc16, WxT16, pb);
    gemm2_reduce<<<dim3(NROWS * 48 / 256), blk, 0, stream>>>(pb, delta, Bm, Cm);
    // 6) chunk-parallel scan (thread-per-d, regs)
    scan_part1_reg<<<dim3(DIN / 256, NC, NB), blk, 0, stream>>>(xc16, delta, Bm, A_log, h_loc, Pc);
    scan_carry<<<dim3(NB * DIN * NST / 256), blk, 0, stream>>>(h_loc, Pc, H_in);
    scan_part3_reg<<<dim3(DIN / 256, NC, NB), blk, 0, stream>>>(xc16, delta, Bm, Cm, A_log, Dp, res16, H_in, y16);
    // 7) W_out (2048x1024) -> Bt3 (1024x2048) fp16
    transpose_to_f16<<<dim3(1024 / 64, 2048 / 64), blk, 0, stream>>>(W_out, Bt3, DIN, DMOD);
    // 8) GEMM3: out = y @ W_out (fp32 out)
    gemm_mfma<0><<<dim3(1024 / 128, NROWS / 128), blk, 0, stream>>>(y16, Bt3, out, nullptr, NROWS, DMOD, DIN);
}